// Round 1
// baseline (154.240 us; speedup 1.0000x reference)
//
#include <hip/hip_runtime.h>

#define G_ 32
#define S_ 512
#define D_ 128
#define H_ 8
#define BM_ (G_*S_)
#define EPSF 1e-6f

typedef float f32x4  __attribute__((ext_vector_type(4)));
typedef float f32x16 __attribute__((ext_vector_type(16)));
typedef short s16x8  __attribute__((ext_vector_type(8)));

typedef unsigned int  uint32;
typedef unsigned short ushort16;

#if __has_builtin(__builtin_amdgcn_exp2f)
#define EXP2F(x) __builtin_amdgcn_exp2f(x)
#else
#define EXP2F(x) exp2f(x)
#endif

static __device__ __forceinline__ unsigned short f2bf(float f){
  uint32 u = __float_as_uint(f);
  u = (u + 0x7fffu + ((u >> 16) & 1u)) >> 16;
  return (unsigned short)u;
}
static __device__ __forceinline__ float bf2f(unsigned short h){
  return __uint_as_float(((uint32)h) << 16);
}
static __device__ __forceinline__ float siluf(float x){
  float e = EXP2F(-x * 1.4426950408889634f);
  return x / (1.0f + e);
}
static __device__ __forceinline__ float geluf(float x){
  float y = 0.7978845608028654f * (x + 0.044715f * x * x * x);
  y = fminf(fmaxf(y, -40.0f), 40.0f);
  float e = EXP2F(y * 2.8853900817779268f);   // e^{2y}
  float th = (e - 1.0f) / (e + 1.0f);
  return 0.5f * x * (1.0f + th);
}

// ---------------- weight transpose + bf16 convert: WT[n][k] = W[k][n] -------
__global__ __launch_bounds__(256) void k_wprep(const float* __restrict__ W,
    unsigned short* __restrict__ WT, int Kd, int Nd){
  int id = blockIdx.x * 256 + threadIdx.x;
  if (id >= Kd * Nd) return;
  int n = id / Kd, k = id - n * Kd;
  WT[id] = f2bf(W[(size_t)k * Nd + n]);
}

// ---------------- RMSNorm (+ optional pe add) -> bf16 ----------------------
template<bool WITH_PE>
__global__ __launch_bounds__(256) void k_rms(const float* __restrict__ x,
    const float* __restrict__ pe, const float* __restrict__ w,
    unsigned short* __restrict__ xnb, unsigned short* __restrict__ qinb){
  const int lane = threadIdx.x & 63, wave = threadIdx.x >> 6;
  const int row = blockIdx.x * 4 + wave;
  const size_t base = (size_t)row * 128 + lane * 2;
  const float2 xv = *(const float2*)&x[base];
  float ss = xv.x * xv.x + xv.y * xv.y;
  #pragma unroll
  for (int off = 1; off < 64; off <<= 1) ss += __shfl_xor(ss, off, 64);
  const float rs = rsqrtf(ss * (1.0f / 128.0f) + EPSF);
  const float2 wv = *(const float2*)&w[lane * 2];
  const float a = xv.x * rs * wv.x, b = xv.y * rs * wv.y;
  ushort2 o; o.x = f2bf(a); o.y = f2bf(b);
  *(ushort2*)&xnb[base] = o;
  if (WITH_PE){
    const float2 pv = *(const float2*)&pe[base];
    ushort2 q; q.x = f2bf(a + pv.x); q.y = f2bf(b + pv.y);
    *(ushort2*)&qinb[base] = q;
  }
}

// ---------------- generic bf16 MFMA GEMM:  C(BM x 128) = A(BM x K) @ WT^T ---
// EPI: 0 = bf16 out (*scale), 1 = f32 out, 2 = f32 out + resid
template<int K, int EPI>
__global__ __launch_bounds__(256) void k_gemm(const unsigned short* __restrict__ A,
    const unsigned short* __restrict__ WT, void* __restrict__ outp,
    const float* __restrict__ resid, float scale){
  const int lane = threadIdx.x & 63, wave = threadIdx.x >> 6;
  const int rowbase = blockIdx.x * 64 + wave * 16;
  const int lr = lane & 15, lh = lane >> 4;
  s16x8 af[K / 32];
  const unsigned short* arow = A + (size_t)(rowbase + lr) * K + lh * 8;
  #pragma unroll
  for (int kc = 0; kc < K / 32; ++kc) af[kc] = *(const s16x8*)(arow + kc * 32);
  #pragma unroll
  for (int ct = 0; ct < 8; ++ct){
    f32x4 acc = (f32x4)(0.0f);
    const unsigned short* wrow = WT + (size_t)(ct * 16 + lr) * K + lh * 8;
    #pragma unroll
    for (int kc = 0; kc < K / 32; ++kc){
      s16x8 bf = *(const s16x8*)(wrow + kc * 32);
      acc = __builtin_amdgcn_mfma_f32_16x16x32_bf16(af[kc], bf, acc, 0, 0, 0);
    }
    #pragma unroll
    for (int j = 0; j < 4; ++j){
      const int row = rowbase + lh * 4 + j;
      const int col = ct * 16 + lr;
      const size_t idx = (size_t)row * 128 + col;
      const float v = acc[j] * scale;
      if (EPI == 0)      ((unsigned short*)outp)[idx] = f2bf(v);
      else if (EPI == 1) ((float*)outp)[idx] = v;
      else               ((float*)outp)[idx] = v + resid[idx];
    }
  }
}

// ---------------- dual GEMM: hh = gelu(A@W1) * (A@W2)  (N=256, bf16 out) ----
__global__ __launch_bounds__(256) void k_gemm_dual(const unsigned short* __restrict__ A,
    const unsigned short* __restrict__ W1T, const unsigned short* __restrict__ W2T,
    unsigned short* __restrict__ out){
  const int lane = threadIdx.x & 63, wave = threadIdx.x >> 6;
  const int rowbase = blockIdx.x * 64 + wave * 16;
  const int colofs = blockIdx.y * 128;
  const int lr = lane & 15, lh = lane >> 4;
  s16x8 af[4];
  const unsigned short* arow = A + (size_t)(rowbase + lr) * 128 + lh * 8;
  #pragma unroll
  for (int kc = 0; kc < 4; ++kc) af[kc] = *(const s16x8*)(arow + kc * 32);
  #pragma unroll
  for (int ct = 0; ct < 8; ++ct){
    f32x4 a1 = (f32x4)(0.0f), a2 = (f32x4)(0.0f);
    const unsigned short* w1 = W1T + (size_t)(colofs + ct * 16 + lr) * 128 + lh * 8;
    const unsigned short* w2 = W2T + (size_t)(colofs + ct * 16 + lr) * 128 + lh * 8;
    #pragma unroll
    for (int kc = 0; kc < 4; ++kc){
      a1 = __builtin_amdgcn_mfma_f32_16x16x32_bf16(af[kc], *(const s16x8*)(w1 + kc * 32), a1, 0, 0, 0);
      a2 = __builtin_amdgcn_mfma_f32_16x16x32_bf16(af[kc], *(const s16x8*)(w2 + kc * 32), a2, 0, 0, 0);
    }
    #pragma unroll
    for (int j = 0; j < 4; ++j){
      const int row = rowbase + lh * 4 + j;
      const int col = colofs + ct * 16 + lr;
      out[(size_t)row * 256 + col] = f2bf(geluf(a1[j]) * a2[j]);
    }
  }
}

// ---------------- gate: gated = silu(g) * o  -> bf16 ------------------------
__global__ __launch_bounds__(256) void k_gate(const float* __restrict__ g,
    const unsigned short* __restrict__ o, unsigned short* __restrict__ out){
  const size_t i = ((size_t)blockIdx.x * 256 + threadIdx.x) * 4;
  const float4 gv = *(const float4*)&g[i];
  const ushort4 ov = *(const ushort4*)&o[i];
  ushort4 r;
  r.x = f2bf(siluf(gv.x) * bf2f(ov.x));
  r.y = f2bf(siluf(gv.y) * bf2f(ov.y));
  r.z = f2bf(siluf(gv.z) * bf2f(ov.z));
  r.w = f2bf(siluf(gv.w) * bf2f(ov.w));
  *(ushort4*)&out[i] = r;
}

// ---------------- retention attention, one (g,h) per block ------------------
// swapped QK^T (mfma(K,Q)) -> lane owns one query column; mask via sad_u8;
// P assembled in-register via cvt_pk_bf16 + shfl_xor(32); PV mfma 32x32x16.
__global__ __launch_bounds__(512, 1) void k_attn(const unsigned short* __restrict__ qb,
    const unsigned short* __restrict__ kb, const unsigned short* __restrict__ vb,
    const int* __restrict__ coords, unsigned short* __restrict__ ob){
  __shared__ unsigned short ql[S_ * 16];
  __shared__ unsigned short kl[S_ * 16];
  __shared__ unsigned short vlT[16 * S_];
  __shared__ uint32 cl1[S_];
  const int g = blockIdx.x >> 3, head = blockIdx.x & 7;
  const int tid = threadIdx.x;
  {
    const size_t rb = (size_t)g * S_ * 128 + head * 16;
    const int t = tid;
    const uint4* qsrc = (const uint4*)(qb + rb + (size_t)t * 128);
    ((uint4*)&ql[t * 16])[0] = qsrc[0];
    ((uint4*)&ql[t * 16])[1] = qsrc[1];
    const uint4* ksrc = (const uint4*)(kb + rb + (size_t)t * 128);
    ((uint4*)&kl[t * 16])[0] = ksrc[0];
    ((uint4*)&kl[t * 16])[1] = ksrc[1];
    const int4 cc = ((const int4*)coords)[g * S_ + t];
    cl1[t] = (uint32)(cc.y & 127) | ((uint32)(cc.z & 127) << 8) | ((uint32)(cc.w & 127) << 16);
    if (tid < 256){
      const int r0 = 2 * tid;
      const unsigned short* v0 = vb + rb + (size_t)r0 * 128;
      const unsigned short* v1 = v0 + 128;
      #pragma unroll
      for (int hd = 0; hd < 16; ++hd){
        const uint32 pk = (uint32)v0[hd] | ((uint32)v1[hd] << 16);
        *(uint32*)&vlT[hd * S_ + r0] = pk;
      }
    }
  }
  __syncthreads();
  const int lane = tid & 63, wave = tid >> 6;
  const int lq = lane & 31, half = lane >> 5;
  const float decay2 = log2f(1.0f - EXP2F(-(float)(5 + head)));
  for (int qi = 0; qi < 2; ++qi){
    const int qt = wave + qi * 8;
    const s16x8 bq = *(const s16x8*)&ql[(qt * 32 + lq) * 16 + half * 8];
    const uint32 cs = cl1[qt * 32 + lq];
    f32x16 accO = (f32x16)(0.0f);
    float Z = 0.f, M = 0.f, W = 0.f;
    for (int tc = 0; tc < 16; ++tc){
      const s16x8 ak = *(const s16x8*)&kl[(tc * 32 + lq) * 16 + half * 8];
      const f32x16 c = __builtin_amdgcn_mfma_f32_32x32x16_bf16(ak, bq, (f32x16)(0.0f), 0, 0, 0);
      float wv[16];
      #pragma unroll
      for (int i = 0; i < 16; ++i){
        const int r = (i & 3) + 8 * (i >> 2) + 4 * half;
        const uint32 ct1 = cl1[tc * 32 + r];
        uint32 dist;
#if __has_builtin(__builtin_amdgcn_sad_u8)
        dist = __builtin_amdgcn_sad_u8(cs, ct1, 0u);
#else
        {
          int dx = (int)(cs & 255)         - (int)(ct1 & 255);
          int dy = (int)((cs >> 8) & 255)  - (int)((ct1 >> 8) & 255);
          int dz = (int)((cs >> 16) & 255) - (int)((ct1 >> 16) & 255);
          dist = (uint32)(abs(dx) + abs(dy) + abs(dz));
        }
#endif
        const float ddl2 = (float)dist * decay2;
        const float e1 = EXP2F(c[i]);       // exp(qk)   (log2e folded into q)
        const float e2 = EXP2F(ddl2);       // exp(dist*decay)
        const float w = e1 * e2;
        Z += e1; M += e2; W += w;
        wv[i] = w;
      }
      uint32 pk[8], oth[8];
      #pragma unroll
      for (int j = 0; j < 8; ++j){
        uint32 p;
        asm("v_cvt_pk_bf16_f32 %0, %1, %2" : "=v"(p) : "v"(wv[2 * j]), "v"(wv[2 * j + 1]));
        pk[j] = p;
        oth[j] = (uint32)__shfl_xor((int)p, 32, 64);
      }
      union { uint32 u[4]; s16x8 v; } f0, f1;
      if (half == 0){
        f0.u[0] = pk[0]; f0.u[1] = pk[1]; f0.u[2] = oth[0]; f0.u[3] = oth[1];
        f1.u[0] = pk[4]; f1.u[1] = pk[5]; f1.u[2] = oth[4]; f1.u[3] = oth[5];
      } else {
        f0.u[0] = oth[2]; f0.u[1] = oth[3]; f0.u[2] = pk[2]; f0.u[3] = pk[3];
        f1.u[0] = oth[6]; f1.u[1] = oth[7]; f1.u[2] = pk[6]; f1.u[3] = pk[7];
      }
      const s16x8 bv0 = *(const s16x8*)&vlT[(lq & 15) * S_ + tc * 32 + half * 8];
      const s16x8 bv1 = *(const s16x8*)&vlT[(lq & 15) * S_ + tc * 32 + 16 + half * 8];
      accO = __builtin_amdgcn_mfma_f32_32x32x16_bf16(f0.v, bv0, accO, 0, 0, 0);
      accO = __builtin_amdgcn_mfma_f32_32x32x16_bf16(f1.v, bv1, accO, 0, 0, 0);
    }
    Z += __shfl_xor(Z, 32, 64);
    M += __shfl_xor(M, 32, 64);
    W += __shfl_xor(W, 32, 64);
    const float zs = Z * sqrtf(M);
    const float denom = fmaxf(1.0f, W / zs);
    const float sc = zs * denom;            // o_true = accO / sc
    const float epsp = EPSF * sc * sc;      // eps compensation for head-RMSNorm
    #pragma unroll
    for (int i = 0; i < 16; ++i){
      const int r = (i & 3) + 8 * (i >> 2) + 4 * half;
      const float v = accO[i];
      float ss = v * v;
      ss += __shfl_xor(ss, 1, 64); ss += __shfl_xor(ss, 2, 64);
      ss += __shfl_xor(ss, 4, 64); ss += __shfl_xor(ss, 8, 64);
      const float ei = __shfl(epsp, r, 64);
      const float on = v * rsqrtf(ss * 0.0625f + ei);
      if (lq < 16)
        ob[((size_t)(g * S_ + qt * 32 + r)) * 128 + head * 16 + lq] = f2bf(on);
    }
  }
}

// ---------------------------------------------------------------------------
extern "C" void kernel_launch(void* const* d_in, const int* in_sizes, int n_in,
                              void* d_out, int out_size, void* d_ws, size_t ws_size,
                              hipStream_t stream){
  const float* x     = (const float*)d_in[0];
  const float* pe    = (const float*)d_in[1];
  const int*   coords= (const int*)d_in[2];
  const float* Wq    = (const float*)d_in[3];
  const float* Wk    = (const float*)d_in[4];
  const float* Wv    = (const float*)d_in[5];
  const float* Wg    = (const float*)d_in[6];
  const float* Wo    = (const float*)d_in[7];
  const float* ln1   = (const float*)d_in[8];
  const float* ln2   = (const float*)d_in[9];
  const float* Wfc1  = (const float*)d_in[10];
  const float* Wgate = (const float*)d_in[11];
  const float* Wfc2  = (const float*)d_in[12];
  float* out = (float*)d_out;
  char* ws = (char*)d_ws;

  const size_t SZB = 4194304;   // BM*128 bf16 bytes
  unsigned short* xnb  = (unsigned short*)(ws);
  unsigned short* qinb = (unsigned short*)(ws + 1 * SZB);
  unsigned short* qbf  = (unsigned short*)(ws + 2 * SZB);
  unsigned short* kbf  = (unsigned short*)(ws + 3 * SZB);
  unsigned short* vbf  = (unsigned short*)(ws + 4 * SZB);
  float*          gbuf = (float*)(ws + 5 * SZB);                 // 8 MB
  unsigned short* obf  = (unsigned short*)(ws + 5 * SZB + 8388608);
  float*          x1   = (float*)(ws + 6 * SZB + 8388608);       // 8 MB
  char* wbase = ws + 6 * SZB + 2 * 8388608;
  unsigned short* wqt   = (unsigned short*)(wbase);
  unsigned short* wkt   = (unsigned short*)(wbase + 32768);
  unsigned short* wvt   = (unsigned short*)(wbase + 65536);
  unsigned short* wgt   = (unsigned short*)(wbase + 98304);
  unsigned short* wot   = (unsigned short*)(wbase + 131072);
  unsigned short* fc1t  = (unsigned short*)(wbase + 163840);
  unsigned short* gatet = (unsigned short*)(wbase + 229376);
  unsigned short* fc2t  = (unsigned short*)(wbase + 294912);
  // buffer reuse after attention:
  unsigned short* gated = xnb;
  unsigned short* hnb   = qinb;
  unsigned short* hhb   = qbf;   // spans qbf..kbf (8 MB)

  dim3 b256(256);
  k_wprep<<<64, b256, 0, stream>>>(Wq, wqt, 128, 128);
  k_wprep<<<64, b256, 0, stream>>>(Wk, wkt, 128, 128);
  k_wprep<<<64, b256, 0, stream>>>(Wv, wvt, 128, 128);
  k_wprep<<<64, b256, 0, stream>>>(Wg, wgt, 128, 128);
  k_wprep<<<64, b256, 0, stream>>>(Wo, wot, 128, 128);
  k_wprep<<<128, b256, 0, stream>>>(Wfc1, fc1t, 128, 256);
  k_wprep<<<128, b256, 0, stream>>>(Wgate, gatet, 128, 256);
  k_wprep<<<128, b256, 0, stream>>>(Wfc2, fc2t, 256, 128);

  k_rms<true><<<4096, b256, 0, stream>>>(x, pe, ln1, xnb, qinb);

  // q has HD^-0.5 * log2(e) folded in so attention uses raw exp2
  k_gemm<128, 0><<<256, b256, 0, stream>>>(qinb, wqt, qbf, nullptr, 0.36067376022224085f);
  k_gemm<128, 0><<<256, b256, 0, stream>>>(qinb, wkt, kbf, nullptr, 1.0f);
  k_gemm<128, 0><<<256, b256, 0, stream>>>(xnb, wvt, vbf, nullptr, 1.0f);
  k_gemm<128, 1><<<256, b256, 0, stream>>>(xnb, wgt, gbuf, nullptr, 1.0f);

  k_attn<<<256, dim3(512), 0, stream>>>(qbf, kbf, vbf, coords, obf);

  k_gate<<<2048, b256, 0, stream>>>(gbuf, obf, gated);
  k_gemm<128, 2><<<256, b256, 0, stream>>>(gated, wot, x1, x, 1.0f);

  k_rms<false><<<4096, b256, 0, stream>>>(x1, nullptr, ln2, hnb, nullptr);
  k_gemm_dual<<<dim3(256, 2), b256, 0, stream>>>(hnb, fc1t, gatet, hhb);
  k_gemm<256, 2><<<256, b256, 0, stream>>>(hhb, fc2t, out, x1, 1.0f);
}

// Round 2
// 126.590 us; speedup vs baseline: 1.2184x; 1.2184x over previous
//
#include <hip/hip_runtime.h>

#define G_ 32
#define S_ 512
#define D_ 128
#define H_ 8
#define BM_ (G_*S_)
#define EPSF 1e-6f
#define VP_ 520   // padded vlT row stride (shorts): breaks bank-set aliasing, keeps 16B align

typedef float f32x4  __attribute__((ext_vector_type(4)));
typedef float f32x16 __attribute__((ext_vector_type(16)));
typedef short s16x8  __attribute__((ext_vector_type(8)));

typedef unsigned int uint32;

#if __has_builtin(__builtin_amdgcn_exp2f)
#define EXP2F(x) __builtin_amdgcn_exp2f(x)
#else
#define EXP2F(x) exp2f(x)
#endif

static __device__ __forceinline__ unsigned short f2bf(float f){
  uint32 u = __float_as_uint(f);
  u = (u + 0x7fffu + ((u >> 16) & 1u)) >> 16;
  return (unsigned short)u;
}
static __device__ __forceinline__ float bf2f(unsigned short h){
  return __uint_as_float(((uint32)h) << 16);
}
static __device__ __forceinline__ float siluf(float x){
  float e = EXP2F(-x * 1.4426950408889634f);
  return x / (1.0f + e);
}
static __device__ __forceinline__ float geluf(float x){
  float y = 0.7978845608028654f * (x + 0.044715f * x * x * x);
  y = fminf(fmaxf(y, -40.0f), 40.0f);
  float e = EXP2F(y * 2.8853900817779268f);   // e^{2y}
  float th = (e - 1.0f) / (e + 1.0f);
  return 0.5f * x * (1.0f + th);
}

// ---------------- all weight transposes in one launch -----------------------
__global__ __launch_bounds__(256) void k_wprep_all(
    const float* __restrict__ w0, const float* __restrict__ w1,
    const float* __restrict__ w2, const float* __restrict__ w3,
    const float* __restrict__ w4, const float* __restrict__ w5,
    const float* __restrict__ w6, const float* __restrict__ w7,
    unsigned short* __restrict__ o0, unsigned short* __restrict__ o1,
    unsigned short* __restrict__ o2, unsigned short* __restrict__ o3,
    unsigned short* __restrict__ o4, unsigned short* __restrict__ o5,
    unsigned short* __restrict__ o6, unsigned short* __restrict__ o7){
  const int which = blockIdx.y;
  const float* W; unsigned short* O; int Kd, Nd;
  switch (which){
    case 0: W = w0; O = o0; Kd = 128; Nd = 128; break;
    case 1: W = w1; O = o1; Kd = 128; Nd = 128; break;
    case 2: W = w2; O = o2; Kd = 128; Nd = 128; break;
    case 3: W = w3; O = o3; Kd = 128; Nd = 128; break;
    case 4: W = w4; O = o4; Kd = 128; Nd = 128; break;
    case 5: W = w5; O = o5; Kd = 128; Nd = 256; break;
    case 6: W = w6; O = o6; Kd = 128; Nd = 256; break;
    default: W = w7; O = o7; Kd = 256; Nd = 128; break;
  }
  const int id = blockIdx.x * 256 + threadIdx.x;
  if (id >= Kd * Nd) return;
  const int n = id / Kd, k = id - n * Kd;
  O[id] = f2bf(W[(size_t)k * Nd + n]);
}

// ---------------- RMSNorm (+ optional pe add) -> bf16 ------------------------
template<bool WITH_PE>
__global__ __launch_bounds__(256) void k_rms(const float* __restrict__ x,
    const float* __restrict__ pe, const float* __restrict__ w,
    unsigned short* __restrict__ xnb, unsigned short* __restrict__ qinb){
  const int lane = threadIdx.x & 63, wave = threadIdx.x >> 6;
  const int row = blockIdx.x * 4 + wave;
  const size_t base = (size_t)row * 128 + lane * 2;
  const float2 xv = *(const float2*)&x[base];
  float ss = xv.x * xv.x + xv.y * xv.y;
  #pragma unroll
  for (int off = 1; off < 64; off <<= 1) ss += __shfl_xor(ss, off, 64);
  const float rs = rsqrtf(ss * (1.0f / 128.0f) + EPSF);
  const float2 wv = *(const float2*)&w[lane * 2];
  const float a = xv.x * rs * wv.x, b = xv.y * rs * wv.y;
  ushort2 o; o.x = f2bf(a); o.y = f2bf(b);
  *(ushort2*)&xnb[base] = o;
  if (WITH_PE){
    const float2 pv = *(const float2*)&pe[base];
    ushort2 q; q.x = f2bf(a + pv.x); q.y = f2bf(b + pv.y);
    *(ushort2*)&qinb[base] = q;
  }
}

// ---------------- generic bf16 MFMA GEMM body --------------------------------
// EPI: 0 = bf16 out (*scale), 2 = f32 out + resid
template<int K, int EPI>
static __device__ __forceinline__ void gemm_body(const unsigned short* __restrict__ A,
    const unsigned short* __restrict__ WT, void* __restrict__ outp,
    const float* __restrict__ resid, float scale, int rowblk){
  const int lane = threadIdx.x & 63, wave = threadIdx.x >> 6;
  const int rowbase = rowblk * 64 + wave * 16;
  const int lr = lane & 15, lh = lane >> 4;
  s16x8 af[K / 32];
  const unsigned short* arow = A + (size_t)(rowbase + lr) * K + lh * 8;
  #pragma unroll
  for (int kc = 0; kc < K / 32; ++kc) af[kc] = *(const s16x8*)(arow + kc * 32);
  #pragma unroll
  for (int ct = 0; ct < 8; ++ct){
    f32x4 acc = (f32x4)(0.0f);
    const unsigned short* wrow = WT + (size_t)(ct * 16 + lr) * K + lh * 8;
    #pragma unroll
    for (int kc = 0; kc < K / 32; ++kc){
      s16x8 bf = *(const s16x8*)(wrow + kc * 32);
      acc = __builtin_amdgcn_mfma_f32_16x16x32_bf16(af[kc], bf, acc, 0, 0, 0);
    }
    #pragma unroll
    for (int j = 0; j < 4; ++j){
      const int row = rowbase + lh * 4 + j;
      const int col = ct * 16 + lr;
      const size_t idx = (size_t)row * 128 + col;
      const float v = acc[j] * scale;
      if (EPI == 0) ((unsigned short*)outp)[idx] = f2bf(v);
      else          ((float*)outp)[idx] = v + resid[idx];
    }
  }
}

template<int K, int EPI>
__global__ __launch_bounds__(256) void k_gemm(const unsigned short* __restrict__ A,
    const unsigned short* __restrict__ WT, void* __restrict__ outp,
    const float* __restrict__ resid, float scale){
  gemm_body<K, EPI>(A, WT, outp, resid, scale, blockIdx.x);
}

// ---------------- fused Q/K/V/G projection (one launch) ----------------------
__global__ __launch_bounds__(256) void k_gemm_qkvg(
    const unsigned short* __restrict__ qinb, const unsigned short* __restrict__ xnb,
    const unsigned short* __restrict__ wqt, const unsigned short* __restrict__ wkt,
    const unsigned short* __restrict__ wvt, const unsigned short* __restrict__ wgt,
    unsigned short* __restrict__ qbf, unsigned short* __restrict__ kbf,
    unsigned short* __restrict__ vbf, unsigned short* __restrict__ gbf){
  const int which = blockIdx.y;
  const unsigned short* A  = (which < 2) ? qinb : xnb;
  const unsigned short* WT = (which == 0) ? wqt : (which == 1) ? wkt : (which == 2) ? wvt : wgt;
  unsigned short* out      = (which == 0) ? qbf : (which == 1) ? kbf : (which == 2) ? vbf : gbf;
  const float scale = (which == 0) ? 0.36067376022224085f : 1.0f;  // HD^-0.5 * log2(e)
  gemm_body<128, 0>(A, WT, (void*)out, nullptr, scale, blockIdx.x);
}

// ---------------- Wo GEMM with fused silu(g)*o A-operand ---------------------
__global__ __launch_bounds__(256) void k_gemm_wo(const unsigned short* __restrict__ g,
    const unsigned short* __restrict__ o, const unsigned short* __restrict__ WT,
    float* __restrict__ outp, const float* __restrict__ resid){
  const int lane = threadIdx.x & 63, wave = threadIdx.x >> 6;
  const int rowbase = blockIdx.x * 64 + wave * 16;
  const int lr = lane & 15, lh = lane >> 4;
  s16x8 af[4];
  const size_t abase = (size_t)(rowbase + lr) * 128 + lh * 8;
  #pragma unroll
  for (int kc = 0; kc < 4; ++kc){
    const s16x8 gv = *(const s16x8*)(g + abase + kc * 32);
    const s16x8 ov = *(const s16x8*)(o + abase + kc * 32);
    s16x8 r;
    #pragma unroll
    for (int j = 0; j < 8; ++j){
      const float gf = bf2f((unsigned short)gv[j]);
      const float of = bf2f((unsigned short)ov[j]);
      r[j] = (short)f2bf(siluf(gf) * of);
    }
    af[kc] = r;
  }
  #pragma unroll
  for (int ct = 0; ct < 8; ++ct){
    f32x4 acc = (f32x4)(0.0f);
    const unsigned short* wrow = WT + (size_t)(ct * 16 + lr) * 128 + lh * 8;
    #pragma unroll
    for (int kc = 0; kc < 4; ++kc)
      acc = __builtin_amdgcn_mfma_f32_16x16x32_bf16(af[kc], *(const s16x8*)(wrow + kc * 32), acc, 0, 0, 0);
    #pragma unroll
    for (int j = 0; j < 4; ++j){
      const int row = rowbase + lh * 4 + j;
      const int col = ct * 16 + lr;
      const size_t idx = (size_t)row * 128 + col;
      outp[idx] = acc[j] + resid[idx];
    }
  }
}

// ---------------- dual GEMM: hh = gelu(A@W1) * (A@W2) ------------------------
__global__ __launch_bounds__(256) void k_gemm_dual(const unsigned short* __restrict__ A,
    const unsigned short* __restrict__ W1T, const unsigned short* __restrict__ W2T,
    unsigned short* __restrict__ out){
  const int lane = threadIdx.x & 63, wave = threadIdx.x >> 6;
  const int rowbase = blockIdx.x * 64 + wave * 16;
  const int colofs = blockIdx.y * 128;
  const int lr = lane & 15, lh = lane >> 4;
  s16x8 af[4];
  const unsigned short* arow = A + (size_t)(rowbase + lr) * 128 + lh * 8;
  #pragma unroll
  for (int kc = 0; kc < 4; ++kc) af[kc] = *(const s16x8*)(arow + kc * 32);
  #pragma unroll
  for (int ct = 0; ct < 8; ++ct){
    f32x4 a1 = (f32x4)(0.0f), a2 = (f32x4)(0.0f);
    const unsigned short* w1 = W1T + (size_t)(colofs + ct * 16 + lr) * 128 + lh * 8;
    const unsigned short* w2 = W2T + (size_t)(colofs + ct * 16 + lr) * 128 + lh * 8;
    #pragma unroll
    for (int kc = 0; kc < 4; ++kc){
      a1 = __builtin_amdgcn_mfma_f32_16x16x32_bf16(af[kc], *(const s16x8*)(w1 + kc * 32), a1, 0, 0, 0);
      a2 = __builtin_amdgcn_mfma_f32_16x16x32_bf16(af[kc], *(const s16x8*)(w2 + kc * 32), a2, 0, 0, 0);
    }
    #pragma unroll
    for (int j = 0; j < 4; ++j){
      const int row = rowbase + lh * 4 + j;
      const int col = colofs + ct * 16 + lr;
      out[(size_t)row * 256 + col] = f2bf(geluf(a1[j]) * a2[j]);
    }
  }
}

// ---------------- retention attention: (g,h,qtile) per block -----------------
// 4 waves/block, 128 q-rows per block; swapped QK^T; padded vlT; 4-shfl P xchg.
__global__ __launch_bounds__(256, 4) void k_attn(const unsigned short* __restrict__ qb,
    const unsigned short* __restrict__ kb, const unsigned short* __restrict__ vb,
    const int* __restrict__ coords, unsigned short* __restrict__ ob){
  __shared__ unsigned short ql[128 * 16];      // 4 KB
  __shared__ unsigned short kl[S_ * 16];       // 16 KB
  __shared__ unsigned short vlT[16 * VP_];     // 16.25 KB (padded rows)
  __shared__ uint32 cl1[S_];                   // 2 KB
  const int bx = blockIdx.x;
  const int g = bx >> 5, head = (bx >> 2) & 7, qtile = bx & 3;
  const int tid = threadIdx.x;
  const size_t rb = (size_t)g * S_ * 128 + head * 16;
  // stage q-tile (128 rows)
  if (tid < 128){
    const uint4* qsrc = (const uint4*)(qb + rb + (size_t)(qtile * 128 + tid) * 128);
    ((uint4*)&ql[tid * 16])[0] = qsrc[0];
    ((uint4*)&ql[tid * 16])[1] = qsrc[1];
  }
  // stage K (512 rows) + packed coords
  #pragma unroll
  for (int r = tid; r < S_; r += 256){
    const uint4* ksrc = (const uint4*)(kb + rb + (size_t)r * 128);
    ((uint4*)&kl[r * 16])[0] = ksrc[0];
    ((uint4*)&kl[r * 16])[1] = ksrc[1];
    const int4 cc = ((const int4*)coords)[g * S_ + r];
    cl1[r] = (uint32)(cc.y & 127) | ((uint32)(cc.z & 127) << 8) | ((uint32)(cc.w & 127) << 16);
  }
  // stage V transposed: vlT[hd][kv] (padded)
  {
    const int r0 = tid * 2;
    const unsigned short* v0 = vb + rb + (size_t)r0 * 128;
    const uint4 a0 = ((const uint4*)v0)[0], a1 = ((const uint4*)v0)[1];
    const uint4 b0 = ((const uint4*)(v0 + 128))[0], b1 = ((const uint4*)(v0 + 128))[1];
    const unsigned short* pa0 = (const unsigned short*)&a0;
    const unsigned short* pa1 = (const unsigned short*)&a1;
    const unsigned short* pb0 = (const unsigned short*)&b0;
    const unsigned short* pb1 = (const unsigned short*)&b1;
    #pragma unroll
    for (int hd = 0; hd < 8; ++hd){
      *(uint32*)&vlT[hd * VP_ + r0] = (uint32)pa0[hd] | ((uint32)pb0[hd] << 16);
      *(uint32*)&vlT[(hd + 8) * VP_ + r0] = (uint32)pa1[hd] | ((uint32)pb1[hd] << 16);
    }
  }
  __syncthreads();
  const int lane = tid & 63, wave = tid >> 6;
  const int lq = lane & 31, half = lane >> 5;
  const int qrow = wave * 32 + lq;                       // local q in [0,128)
  const float decay2 = log2f(1.0f - EXP2F(-(float)(5 + head)));
  const s16x8 bq = *(const s16x8*)&ql[qrow * 16 + half * 8];
  const uint32 cs = cl1[qtile * 128 + qrow];
  f32x16 accO = (f32x16)(0.0f);
  float Z = 0.f, M = 0.f, W = 0.f;
  for (int tc = 0; tc < 16; ++tc){
    const s16x8 ak = *(const s16x8*)&kl[(tc * 32 + lq) * 16 + half * 8];
    const f32x16 c = __builtin_amdgcn_mfma_f32_32x32x16_bf16(ak, bq, (f32x16)(0.0f), 0, 0, 0);
    float wv[16];
    #pragma unroll
    for (int i = 0; i < 16; ++i){
      const int r = (i & 3) + 8 * (i >> 2) + 4 * half;
      const uint32 ct1 = cl1[tc * 32 + r];
      uint32 dist;
#if __has_builtin(__builtin_amdgcn_sad_u8)
      dist = __builtin_amdgcn_sad_u8(cs, ct1, 0u);
#else
      {
        int dx = (int)(cs & 255)         - (int)(ct1 & 255);
        int dy = (int)((cs >> 8) & 255)  - (int)((ct1 >> 8) & 255);
        int dz = (int)((cs >> 16) & 255) - (int)((ct1 >> 16) & 255);
        dist = (uint32)(abs(dx) + abs(dy) + abs(dz));
      }
#endif
      const float ddl2 = (float)dist * decay2;
      const float e1 = EXP2F(c[i]);       // exp(qk)   (log2e folded into q)
      const float e2 = EXP2F(ddl2);       // exp(dist*decay)
      const float w = e1 * e2;
      Z += e1; M += e2; W += w;
      wv[i] = w;
    }
    uint32 pk[8];
    #pragma unroll
    for (int j = 0; j < 8; ++j){
      uint32 p;
      asm("v_cvt_pk_bf16_f32 %0, %1, %2" : "=v"(p) : "v"(wv[2 * j]), "v"(wv[2 * j + 1]));
      pk[j] = p;
    }
    // exchange only the 4 words each half actually needs
    uint32 oth[4];
    {
      const uint32 s0 = half ? pk[0] : pk[2];
      const uint32 s1 = half ? pk[1] : pk[3];
      const uint32 s2 = half ? pk[4] : pk[6];
      const uint32 s3 = half ? pk[5] : pk[7];
      oth[0] = (uint32)__shfl_xor((int)s0, 32, 64);
      oth[1] = (uint32)__shfl_xor((int)s1, 32, 64);
      oth[2] = (uint32)__shfl_xor((int)s2, 32, 64);
      oth[3] = (uint32)__shfl_xor((int)s3, 32, 64);
    }
    union { uint32 u[4]; s16x8 v; } f0, f1;
    if (half == 0){
      f0.u[0] = pk[0]; f0.u[1] = pk[1]; f0.u[2] = oth[0]; f0.u[3] = oth[1];
      f1.u[0] = pk[4]; f1.u[1] = pk[5]; f1.u[2] = oth[2]; f1.u[3] = oth[3];
    } else {
      f0.u[0] = oth[0]; f0.u[1] = oth[1]; f0.u[2] = pk[2]; f0.u[3] = pk[3];
      f1.u[0] = oth[2]; f1.u[1] = oth[3]; f1.u[2] = pk[6]; f1.u[3] = pk[7];
    }
    const s16x8 bv0 = *(const s16x8*)&vlT[(lq & 15) * VP_ + tc * 32 + half * 8];
    const s16x8 bv1 = *(const s16x8*)&vlT[(lq & 15) * VP_ + tc * 32 + 16 + half * 8];
    accO = __builtin_amdgcn_mfma_f32_32x32x16_bf16(f0.v, bv0, accO, 0, 0, 0);
    accO = __builtin_amdgcn_mfma_f32_32x32x16_bf16(f1.v, bv1, accO, 0, 0, 0);
  }
  Z += __shfl_xor(Z, 32, 64);
  M += __shfl_xor(M, 32, 64);
  W += __shfl_xor(W, 32, 64);
  const float zs = Z * sqrtf(M);
  const float denom = fmaxf(1.0f, W / zs);
  const float sc = zs * denom;            // o_true = accO / sc
  const float epsp = EPSF * sc * sc;      // eps compensation for head-RMSNorm
  const size_t qbase = (size_t)(g * S_ + qtile * 128 + wave * 32);
  #pragma unroll
  for (int i = 0; i < 16; ++i){
    const int r = (i & 3) + 8 * (i >> 2) + 4 * half;
    const float v = accO[i];
    float ss = v * v;
    ss += __shfl_xor(ss, 1, 64); ss += __shfl_xor(ss, 2, 64);
    ss += __shfl_xor(ss, 4, 64); ss += __shfl_xor(ss, 8, 64);
    const float ei = __shfl(epsp, r, 64);
    const float on = v * rsqrtf(ss * 0.0625f + ei);
    if (lq < 16)
      ob[(qbase + r) * 128 + head * 16 + lq] = f2bf(on);
  }
}

// ---------------------------------------------------------------------------
extern "C" void kernel_launch(void* const* d_in, const int* in_sizes, int n_in,
                              void* d_out, int out_size, void* d_ws, size_t ws_size,
                              hipStream_t stream){
  const float* x     = (const float*)d_in[0];
  const float* pe    = (const float*)d_in[1];
  const int*   coords= (const int*)d_in[2];
  const float* Wq    = (const float*)d_in[3];
  const float* Wk    = (const float*)d_in[4];
  const float* Wv    = (const float*)d_in[5];
  const float* Wg    = (const float*)d_in[6];
  const float* Wo    = (const float*)d_in[7];
  const float* ln1   = (const float*)d_in[8];
  const float* ln2   = (const float*)d_in[9];
  const float* Wfc1  = (const float*)d_in[10];
  const float* Wgate = (const float*)d_in[11];
  const float* Wfc2  = (const float*)d_in[12];
  float* out = (float*)d_out;
  char* ws = (char*)d_ws;

  const size_t SZB = 4194304;   // BM*128 bf16 bytes
  unsigned short* xnb  = (unsigned short*)(ws);
  unsigned short* qinb = (unsigned short*)(ws + 1 * SZB);
  unsigned short* qbf  = (unsigned short*)(ws + 2 * SZB);
  unsigned short* kbf  = (unsigned short*)(ws + 3 * SZB);
  unsigned short* vbf  = (unsigned short*)(ws + 4 * SZB);
  unsigned short* gbf  = (unsigned short*)(ws + 5 * SZB);
  unsigned short* obf  = (unsigned short*)(ws + 6 * SZB);
  float*          x1   = (float*)(ws + 7 * SZB);          // 8 MB f32
  char* wbase = ws + 7 * SZB + 8388608;
  unsigned short* wqt   = (unsigned short*)(wbase);
  unsigned short* wkt   = (unsigned short*)(wbase + 32768);
  unsigned short* wvt   = (unsigned short*)(wbase + 65536);
  unsigned short* wgt   = (unsigned short*)(wbase + 98304);
  unsigned short* wot   = (unsigned short*)(wbase + 131072);
  unsigned short* fc1t  = (unsigned short*)(wbase + 163840);
  unsigned short* gatet = (unsigned short*)(wbase + 229376);
  unsigned short* fc2t  = (unsigned short*)(wbase + 294912);
  // buffer reuse after attention:
  unsigned short* hnb = xnb;
  unsigned short* hhb = qbf;    // 8 MB spans qbf..kbf

  dim3 b256(256);
  k_wprep_all<<<dim3(128, 8), b256, 0, stream>>>(Wq, Wk, Wv, Wg, Wo, Wfc1, Wgate, Wfc2,
                                                 wqt, wkt, wvt, wgt, wot, fc1t, gatet, fc2t);
  k_rms<true><<<4096, b256, 0, stream>>>(x, pe, ln1, xnb, qinb);
  k_gemm_qkvg<<<dim3(256, 4), b256, 0, stream>>>(qinb, xnb, wqt, wkt, wvt, wgt,
                                                 qbf, kbf, vbf, gbf);
  k_attn<<<1024, b256, 0, stream>>>(qbf, kbf, vbf, coords, obf);
  k_gemm_wo<<<256, b256, 0, stream>>>(gbf, obf, wot, x1, x);
  k_rms<false><<<4096, b256, 0, stream>>>(x1, nullptr, ln2, hnb, nullptr);
  k_gemm_dual<<<dim3(256, 2), b256, 0, stream>>>(hnb, fc1t, gatet, hhb);
  k_gemm<256, 2><<<256, b256, 0, stream>>>(hhb, fc2t, out, x1, 1.0f);
}